// Round 6
// baseline (205.511 us; speedup 1.0000x reference)
//
#include <hip/hip_runtime.h>
#include <math.h>

#define B_ 4
#define D_ 256
#define N_ 2048
#define H_ 4

typedef __attribute__((ext_vector_type(8))) __bf16 bf16x8;
typedef __attribute__((ext_vector_type(4))) __bf16 bf16x4;
typedef __attribute__((ext_vector_type(4))) float f32x4;

// ---------------------------------------------------------------------------
// MFMA bf16 conv1x1 tile, double-buffered LDS (1 barrier per K-step) +
// W-fragment prefetch. Layout identical to round 5 otherwise.
// ---------------------------------------------------------------------------
__device__ __forceinline__ void conv_tile(
    const float* __restrict__ in1, int C1,
    const float* __restrict__ in2, int C2,
    const float* __restrict__ Wt, const float* __restrict__ bias,
    float* __restrict__ out, int Cout, int K, int RELU,
    int b, int o0, int n0, __bf16 (*sXT)[64][72])
{
    const int t = threadIdx.x;
    const int w  = t >> 6;
    const int g  = (t >> 4) & 3;
    const int c16 = t & 15;
    const int d_ld = t & 63;
    const int wv   = t >> 6;

    f32x4 acc[4];
#pragma unroll
    for (int i = 0; i < 4; ++i) acc[i] = (f32x4){0.f, 0.f, 0.f, 0.f};

    float4 xreg[4];
    float4 wreg[4];
    const int ow = o0 + 16 * w + c16;

    auto LOADX = [&](int ks) {
        const int ch = ks + d_ld;
        const float* src = (ch < C1)
            ? in1 + ((size_t)b * C1 + ch) * N_ + n0 + wv * 16
            : in2 + ((size_t)b * C2 + (ch - C1)) * N_ + n0 + wv * 16;
#pragma unroll
        for (int j = 0; j < 4; ++j) xreg[j] = *(const float4*)&src[4 * j];
    };
    auto LOADW = [&](int ks) {
        wreg[0] = *(const float4*)&Wt[(size_t)ow * K + ks + 8 * g];
        wreg[1] = *(const float4*)&Wt[(size_t)ow * K + ks + 8 * g + 4];
        wreg[2] = *(const float4*)&Wt[(size_t)ow * K + ks + 32 + 8 * g];
        wreg[3] = *(const float4*)&Wt[(size_t)ow * K + ks + 32 + 8 * g + 4];
    };
    auto WRITEXT = [&](int buf) {
#pragma unroll
        for (int j = 0; j < 4; ++j) {
            const float xf[4] = {xreg[j].x, xreg[j].y, xreg[j].z, xreg[j].w};
#pragma unroll
            for (int i = 0; i < 4; ++i)
                sXT[buf][wv * 16 + 4 * j + i][d_ld] = (__bf16)xf[i];
        }
    };

    LOADX(0);
    LOADW(0);
    WRITEXT(0);
    __syncthreads();

    const int nsteps = K >> 6;
    for (int s = 0; s < nsteps; ++s) {
        const int cur = s & 1;
        const int ks = s << 6;
        if (s + 1 < nsteps) LOADX(ks + 64);

        // consume current W regs into fragments, then prefetch next W
        bf16x8 af[2];
#pragma unroll
        for (int kc = 0; kc < 2; ++kc) {
            const float* w0 = (const float*)&wreg[2 * kc];
            const float* w1 = (const float*)&wreg[2 * kc + 1];
#pragma unroll
            for (int i = 0; i < 4; ++i) {
                af[kc][i]     = (__bf16)w0[i];
                af[kc][i + 4] = (__bf16)w1[i];
            }
        }
        if (s + 1 < nsteps) LOADW(ks + 64);

#pragma unroll
        for (int kc = 0; kc < 2; ++kc)
#pragma unroll
            for (int nsub = 0; nsub < 4; ++nsub) {
                const bf16x8 bfr = *(const bf16x8*)&sXT[cur][16 * nsub + c16][32 * kc + 8 * g];
                acc[nsub] = __builtin_amdgcn_mfma_f32_16x16x32_bf16(af[kc], bfr, acc[nsub], 0, 0, 0);
            }

        if (s + 1 < nsteps) WRITEXT(cur ^ 1);
        __syncthreads();
    }

#pragma unroll
    for (int nsub = 0; nsub < 4; ++nsub)
#pragma unroll
        for (int r = 0; r < 4; ++r) {
            const int o = o0 + 16 * w + 4 * g + r;
            float v = acc[nsub][r] + bias[o];
            if (RELU) v = fmaxf(v, 0.f);
            out[((size_t)b * Cout + o) * N_ + n0 + 16 * nsub + c16] = v;
        }
}

template <int RELU>
__global__ __launch_bounds__(256) void mfma_conv_kernel(
    const float* __restrict__ in1, int C1,
    const float* __restrict__ in2, int C2,
    const float* __restrict__ W, const float* __restrict__ bias,
    float* __restrict__ out, int Cout, int K)
{
    __shared__ __bf16 sXT[2][64][72];
    conv_tile(in1, C1, in2, C2, W, bias, out, Cout, K, RELU,
              blockIdx.z, blockIdx.y * 64, blockIdx.x * 64, sXT);
}

// Fused Q/K/V projections: blockIdx.y in [0,12): sel = y>>2 picks {q,k,v}.
__global__ __launch_bounds__(256) void qkv_conv_kernel(
    const float* __restrict__ x, const float* __restrict__ source,
    const float* __restrict__ Wq, const float* __restrict__ bq,
    const float* __restrict__ Wk, const float* __restrict__ bk,
    const float* __restrict__ Wv, const float* __restrict__ bv,
    float* __restrict__ Qo, float* __restrict__ Ko, float* __restrict__ Vo)
{
    __shared__ __bf16 sXT[2][64][72];
    const int sel = blockIdx.y >> 2;
    const int o0  = (blockIdx.y & 3) * 64;
    const float* in = (sel == 0) ? x : source;
    const float* W  = (sel == 0) ? Wq : (sel == 1) ? Wk : Wv;
    const float* bs = (sel == 0) ? bq : (sel == 1) ? bk : bv;
    float* out      = (sel == 0) ? Qo : (sel == 1) ? Ko : Vo;
    conv_tile(in, D_, nullptr, 0, W, bs, out, D_, D_, 0,
              blockIdx.z, o0, blockIdx.x * 64, sXT);
}

// ---------------------------------------------------------------------------
// MFMA bf16 fused attention, m-split flash style, with pi-permuted K rows:
// sKT slot s holds K-row m with pi(m) = 16*(m&3) + (m>>2), so QK^T's
// C-column c16 (msub loop) corresponds to m = 4*c16 + msub (contiguous!).
// => edge loads are float4, sP writes are bf16x4, V/PV layouts unchanged
// (m-order consistent on both PV operands; softmax is m-permutation-invariant).
// ---------------------------------------------------------------------------
template <int NSPLIT>
__global__ __launch_bounds__(256, 4) void attn_kernel(
    const float* __restrict__ Qg, const float* __restrict__ Kg,
    const float* __restrict__ Vg, const float* __restrict__ edge,
    __bf16* __restrict__ OP, float* __restrict__ ML)
{
    const int nt    = blockIdx.x;
    const int n0    = nt * 64;
    const int split = blockIdx.y % NSPLIT;
    const int h     = blockIdx.y / NSPLIT;
    const int b     = blockIdx.z;
    const int t  = threadIdx.x;
    const int w  = t >> 6;
    const int g  = (t >> 4) & 3;
    const int c16 = t & 15;

    const int MT   = 32 / NSPLIT;
    const int m_lo = split * (N_ / NSPLIT);
    const int pid  = ((b * H_ + h) * NSPLIT + split) * 32 + nt;

    __shared__ __bf16 sKT[64][72];
    __shared__ __bf16 sP [64][72];
    __shared__ float  sF[64];

    bf16x8 qf[2];
#pragma unroll
    for (int kc = 0; kc < 2; ++kc)
#pragma unroll
        for (int e = 0; e < 8; ++e) {
            const int d = 32 * kc + 8 * g + e;
            qf[kc][e] = (__bf16)(0.125f *
                Qg[((size_t)b * D_ + d * H_ + h) * N_ + n0 + 16 * w + c16]);
        }

    f32x4 acc[4];
#pragma unroll
    for (int i = 0; i < 4; ++i) acc[i] = (f32x4){0.f, 0.f, 0.f, 0.f};
    float M[4], Lr[4];
#pragma unroll
    for (int r = 0; r < 4; ++r) { M[r] = -3.0e38f; Lr[r] = 0.f; }

    const int d_ld = t & 63;
    const int wv   = t >> 6;
    const size_t kbase = ((size_t)b * D_ + d_ld * H_ + h) * N_ + m_lo + wv * 16;
    const size_t vrow = ((size_t)b * D_ + (16 * w + c16) * H_ + h) * N_ + m_lo;
    // edge: rows n0+16w+4g+r, cols m_lo + m0 + 4*c16 .. +3 (float4)
    const size_t ebase = ((size_t)b * N_ + n0 + 16 * w + 4 * g) * N_ + m_lo + 4 * c16;

    float4 kreg[4];
    float4 vreg[4];
    float4 ereg[4];  // [r] -> edge[m0 + 4*c16 + 0..3]

    auto LOADK = [&](int m0) {
#pragma unroll
        for (int j = 0; j < 4; ++j) kreg[j] = *(const float4*)&Kg[kbase + m0 + 4 * j];
    };
    auto LOADV = [&](int m0) {
        vreg[0] = *(const float4*)&Vg[vrow + m0 + 8 * g];
        vreg[1] = *(const float4*)&Vg[vrow + m0 + 8 * g + 4];
        vreg[2] = *(const float4*)&Vg[vrow + m0 + 32 + 8 * g];
        vreg[3] = *(const float4*)&Vg[vrow + m0 + 32 + 8 * g + 4];
    };
    auto LOADE = [&](int m0) {
#pragma unroll
        for (int r = 0; r < 4; ++r)
            ereg[r] = *(const float4*)&edge[ebase + (size_t)r * N_ + m0];
    };
    // pi-permuted K staging: m = 16wv+4j+i -> slot 16i+4wv+j
    auto WRITEKT = [&]() {
#pragma unroll
        for (int j = 0; j < 4; ++j) {
            const float kf[4] = {kreg[j].x, kreg[j].y, kreg[j].z, kreg[j].w};
#pragma unroll
            for (int i = 0; i < 4; ++i)
                sKT[16 * i + 4 * wv + j][d_ld] = (__bf16)kf[i];
        }
    };

    LOADK(0);
    LOADV(0);
    LOADE(0);
    WRITEKT();
    __syncthreads();

    for (int mt = 0; mt < MT; ++mt) {
        const int m0n = (mt < MT - 1 ? mt + 1 : mt) * 64;

        LOADK(m0n);
        bf16x8 af[2];
#pragma unroll
        for (int kc = 0; kc < 2; ++kc)
#pragma unroll
            for (int e = 0; e < 8; ++e) {
                const float* vp = (const float*)&vreg[2 * kc + (e >> 2)];
                af[kc][e] = (__bf16)vp[e & 3];
            }
        LOADV(m0n);

        // ---- QK^T: sfrag[msub][r] = S[n=16w+4g+r][m = m0 + 4*c16 + msub] ----
        f32x4 sfrag[4];
#pragma unroll
        for (int msub = 0; msub < 4; ++msub) {
            f32x4 s = (f32x4){0.f, 0.f, 0.f, 0.f};
#pragma unroll
            for (int kc = 0; kc < 2; ++kc) {
                const bf16x8 bfr = *(const bf16x8*)&sKT[16 * msub + c16][32 * kc + 8 * g];
                s = __builtin_amdgcn_mfma_f32_16x16x32_bf16(qf[kc], bfr, s, 0, 0, 0);
            }
            sfrag[msub] = s;
        }

        // defer-max online softmax
        float rm[4];
#pragma unroll
        for (int r = 0; r < 4; ++r)
            rm[r] = fmaxf(fmaxf(sfrag[0][r], sfrag[1][r]),
                          fmaxf(sfrag[2][r], sfrag[3][r]));
        int need = 0;
#pragma unroll
        for (int r = 0; r < 4; ++r) need |= (rm[r] > M[r] + 8.0f) ? 1 : 0;

        float fr[4];
        if (__any(need)) {
#pragma unroll
            for (int mask = 1; mask < 16; mask <<= 1)
#pragma unroll
                for (int r = 0; r < 4; ++r)
                    rm[r] = fmaxf(rm[r], __shfl_xor(rm[r], mask));
#pragma unroll
            for (int r = 0; r < 4; ++r) {
                const float Mn = fmaxf(M[r], rm[r]);
                fr[r] = __expf(M[r] - Mn);
                M[r]  = Mn;
                Lr[r] *= fr[r];
            }
        } else {
#pragma unroll
            for (int r = 0; r < 4; ++r) fr[r] = 1.0f;
        }
        if (c16 == 0) {
#pragma unroll
            for (int r = 0; r < 4; ++r) sF[16 * w + 4 * g + r] = fr[r];
        }

        // p = exp(s - M); L += p; sP[n][4*c16 + msub] = bf16(p * edge)
#pragma unroll
        for (int r = 0; r < 4; ++r) {
            const int nloc = 16 * w + 4 * g + r;
            const float ef[4] = {ereg[r].x, ereg[r].y, ereg[r].z, ereg[r].w};
            bf16x4 pe;
#pragma unroll
            for (int msub = 0; msub < 4; ++msub) {
                const float p = __expf(sfrag[msub][r] - M[r]);
                Lr[r] += p;
                pe[msub] = (__bf16)(p * ef[msub]);
            }
            *(bf16x4*)&sP[nloc][4 * c16] = pe;
        }
        LOADE(m0n);

        __syncthreads();

#pragma unroll
        for (int nsub = 0; nsub < 4; ++nsub) {
            const float f = sF[16 * nsub + c16];
            acc[nsub] *= f;
        }
#pragma unroll
        for (int kc = 0; kc < 2; ++kc) {
#pragma unroll
            for (int nsub = 0; nsub < 4; ++nsub) {
                const bf16x8 bfr = *(const bf16x8*)&sP[16 * nsub + c16][32 * kc + 8 * g];
                acc[nsub] = __builtin_amdgcn_mfma_f32_16x16x32_bf16(af[kc], bfr, acc[nsub], 0, 0, 0);
            }
        }
        WRITEKT();

        __syncthreads();
    }

#pragma unroll
    for (int mask = 1; mask < 16; mask <<= 1)
#pragma unroll
        for (int r = 0; r < 4; ++r) Lr[r] += __shfl_xor(Lr[r], mask);
    if (c16 == 0) {
#pragma unroll
        for (int r = 0; r < 4; ++r) {
            const int nloc = 16 * w + 4 * g + r;
            ML[(size_t)pid * 128 + nloc]      = M[r];
            ML[(size_t)pid * 128 + 64 + nloc] = Lr[r];
        }
    }
#pragma unroll
    for (int nsub = 0; nsub < 4; ++nsub)
#pragma unroll
        for (int r = 0; r < 4; ++r) {
            const int dd = 16 * w + 4 * g + r;
            OP[(size_t)pid * 4096 + dd * 64 + 16 * nsub + c16] = (__bf16)acc[nsub][r];
        }
}

// ---------------------------------------------------------------------------
// Combine m-split partials.
// ---------------------------------------------------------------------------
template <int NSPLIT>
__global__ __launch_bounds__(256) void combine_kernel(
    const __bf16* __restrict__ OP, const float* __restrict__ ML,
    float* __restrict__ msg)
{
    const int nt = blockIdx.x;
    const int h  = blockIdx.y;
    const int b  = blockIdx.z;
    const int t  = threadIdx.x;
    const int d  = t & 63;
    const int seg = t >> 6;
    const int pid0 = ((b * H_ + h) * NSPLIT) * 32 + nt;

    __shared__ float sM[NSPLIT][64], sL[NSPLIT][64];
    if (t < NSPLIT * 64) {
        const int s = t >> 6, n = t & 63;
        sM[s][n] = ML[(size_t)(pid0 + s * 32) * 128 + n];
        sL[s][n] = ML[(size_t)(pid0 + s * 32) * 128 + 64 + n];
    }
    __syncthreads();

#pragma unroll
    for (int q = 0; q < 4; ++q) {
        const int c0 = seg * 16 + q * 4;
        float o[4] = {0.f, 0.f, 0.f, 0.f};
        float wgt[NSPLIT][4];
#pragma unroll
        for (int j = 0; j < 4; ++j) {
            float mx = -3.0e38f;
            for (int s = 0; s < NSPLIT; ++s) mx = fmaxf(mx, sM[s][c0 + j]);
            float den = 0.f;
            for (int s = 0; s < NSPLIT; ++s) {
                wgt[s][j] = __expf(sM[s][c0 + j] - mx);
                den += wgt[s][j] * sL[s][c0 + j];
            }
            const float inv = 1.0f / den;
            for (int s = 0; s < NSPLIT; ++s) wgt[s][j] *= inv;
        }
        for (int s = 0; s < NSPLIT; ++s) {
            const bf16x4 a = *(const bf16x4*)&OP[(size_t)(pid0 + s * 32) * 4096 + d * 64 + c0];
#pragma unroll
            for (int j = 0; j < 4; ++j) o[j] += wgt[s][j] * (float)a[j];
        }
        float4 r = {o[0], o[1], o[2], o[3]};
        *(float4*)&msg[((size_t)b * D_ + d * H_ + h) * N_ + nt * 64 + c0] = r;
    }
}

// ---------------------------------------------------------------------------
extern "C" void kernel_launch(void* const* d_in, const int* in_sizes, int n_in,
                              void* d_out, int out_size, void* d_ws, size_t ws_size,
                              hipStream_t stream) {
    const float* x      = (const float*)d_in[0];
    const float* source = (const float*)d_in[1];
    const float* edge   = (const float*)d_in[2];
    const float* Wq = (const float*)d_in[3];
    const float* bq = (const float*)d_in[4];
    const float* Wk = (const float*)d_in[5];
    const float* bk = (const float*)d_in[6];
    const float* Wv = (const float*)d_in[7];
    const float* bv = (const float*)d_in[8];
    const float* Wm = (const float*)d_in[9];
    const float* bm = (const float*)d_in[10];
    const float* W1 = (const float*)d_in[11];
    const float* b1 = (const float*)d_in[12];
    const float* W2 = (const float*)d_in[13];
    const float* b2 = (const float*)d_in[14];
    float* out = (float*)d_out;

    const size_t BDN = (size_t)B_ * D_ * N_;
    float* Qw  = (float*)d_ws;
    float* Kw  = Qw + BDN;
    float* Vw  = Kw + BDN;
    float* MSG = Vw + BDN;
    float* MES = MSG + BDN;
    float* H1  = MES + BDN;           // 2*BDN floats
    char*  tail = (char*)(H1 + 2 * BDN);
    const size_t baseBytes = (size_t)7 * BDN * 4;

    const dim3 blk(256);
    const dim3 gD(N_ / 64, D_ / 64, B_);
    const dim3 g2D(N_ / 64, 2 * D_ / 64, B_);

    qkv_conv_kernel<<<dim3(N_ / 64, 12, B_), blk, 0, stream>>>(
        x, source, Wq, bq, Wk, bk, Wv, bv, Qw, Kw, Vw);

    auto needFor = [&](int ns) {
        const size_t pids = (size_t)ns * B_ * H_ * 32;
        return baseBytes + pids * 4096 * 2 + pids * 128 * 4;
    };
    if (ws_size >= needFor(2)) {
        const size_t pids = (size_t)2 * B_ * H_ * 32;
        __bf16* OP = (__bf16*)tail;
        float*  ML = (float*)(tail + pids * 4096 * 2);
        attn_kernel<2><<<dim3(32, H_ * 2, B_), blk, 0, stream>>>(Qw, Kw, Vw, edge, OP, ML);
        combine_kernel<2><<<dim3(32, H_, B_), blk, 0, stream>>>(OP, ML, MSG);
    } else {
        const size_t pids = (size_t)B_ * H_ * 32;
        __bf16* OP = (__bf16*)tail;
        float*  ML = (float*)(tail + pids * 4096 * 2);
        attn_kernel<1><<<dim3(32, H_, B_), blk, 0, stream>>>(Qw, Kw, Vw, edge, OP, ML);
        combine_kernel<1><<<dim3(32, H_, B_), blk, 0, stream>>>(OP, ML, MSG);
    }

    mfma_conv_kernel<0><<<gD, blk, 0, stream>>>(MSG, D_, nullptr, 0, Wm, bm, MES, D_, D_);
    mfma_conv_kernel<1><<<g2D, blk, 0, stream>>>(x, D_, MES, D_, W1, b1, H1, 2 * D_, 2 * D_);
    mfma_conv_kernel<0><<<gD, blk, 0, stream>>>(H1, 2 * D_, nullptr, 0, W2, b2, out, D_, 2 * D_);
}